// Round 8
// baseline (280.941 us; speedup 1.0000x reference)
//
#include <hip/hip_runtime.h>
#include <cstddef>

typedef _Float16 f16;
typedef _Float16 f16x8 __attribute__((ext_vector_type(8)));
typedef _Float16 f16x4 __attribute__((ext_vector_type(4)));
typedef _Float16 f16x2 __attribute__((ext_vector_type(2)));
typedef float f32x4 __attribute__((ext_vector_type(4)));
typedef float f32x16 __attribute__((ext_vector_type(16)));
typedef unsigned int u32;

__device__ inline float exp2_fast(float x) {
  float r;
  asm("v_exp_f32 %0, %1" : "=v"(r) : "v"(x));
  return r;
}

// ---------------------------------------------------------------------------
// Fused prep: blocks [0,8192) stream-convert x_q/x_kv f32->f16;
// blocks [8192,12288) transpose+convert the three weight matrices.
// ---------------------------------------------------------------------------
__global__ __launch_bounds__(256) void prep(
    const float* __restrict__ xq, const float* __restrict__ xkv,
    f16* __restrict__ oq, f16* __restrict__ okv,
    const float* __restrict__ Wq, const float* __restrict__ Wkv,
    const float* __restrict__ Wp, f16* __restrict__ Wqt,
    f16* __restrict__ Wkvt, f16* __restrict__ Wpt) {
  __shared__ float t[32][33];
  int bid = blockIdx.x;
  if (bid < 8192) {
    const float* in = (bid < 4096) ? xq : xkv;
    f16* out = (bid < 4096) ? oq : okv;
    int i = ((bid & 4095) * 256 + threadIdx.x) * 4;
    float4 v = *(const float4*)&in[i];
    f16x4 h;
    h[0] = (f16)v.x; h[1] = (f16)v.y; h[2] = (f16)v.z; h[3] = (f16)v.w;
    *(f16x4*)&out[i] = h;
  } else {
    int zz = bid - 8192;
    int bx = zz & 31, by = (zz >> 5) & 31, z = zz >> 10;
    const float* in;
    f16* out;
    int N = 1024, extra = 0;
    if (z == 0) { in = Wq; out = Wqt; }
    else if (z == 3) { in = Wp; out = Wpt; }
    else { in = Wkv; out = Wkvt; N = 2048; extra = (z - 1) * 1024; }
    int tx = threadIdx.x % 32, ty = threadIdx.x / 32;
    int n0 = bx * 32 + extra, k0 = by * 32;
#pragma unroll
    for (int i = 0; i < 32; i += 8)
      t[ty + i][tx] = in[(size_t)(k0 + ty + i) * N + n0 + tx];
    __syncthreads();
#pragma unroll
    for (int i = 0; i < 32; i += 8)
      out[(size_t)(n0 + ty + i) * 1024 + k0 + tx] = (f16)t[tx][ty + i];
  }
}

// ---------------------------------------------------------------------------
// GEMM, round 8: barrier-free direct-global (flatmm-style).
// C = scale*(A @ W), Bt = W^T f16 [N][K], A f16 [M][K]. No LDS, no barriers.
// Block = 4 waves (2x2) -> 128x128 block tile; each wave owns a 64x64 C tile
// via 4x4 of 16x16x32 MFMA. Fragments are read DIRECTLY from global:
// lane reads 16B (dwordx4) at row(m or n)*K + quad*8 + k; K is a template
// constant so the fully-unrolled K-loop uses immediate offsets (<= 1984 B,
// fits the 13-bit signed field) -- zero address math in the loop.
// Rationale: with BK-tiling each block reads its A/B strips exactly once
// whether or not they bounce through LDS (in-register frag reuse covers the
// 4x4 tile), so LDS staging only added barrier drains, bank traffic, and
// spill pressure. Depth-1 register prefetch + ~3 waves/SIMD hides L2 latency.
// Grid: n-stripe = bid % nb maps round-robin to XCDs, so each XCD's L2 keeps
// one ~256 KB weight strip resident.
// ---------------------------------------------------------------------------
template <int K, typename CT>
__device__ __forceinline__ void gemm_direct(
    const f16* __restrict__ A, const f16* __restrict__ Bt, CT* __restrict__ C,
    int bid, int N, float scale) {
  const int nb = N >> 7;
  const int m0 = (bid / nb) << 7;
  const int n0 = (bid % nb) << 7;
  const int tid = threadIdx.x;
  const int w = tid >> 6, lane = tid & 63;
  const int l16 = lane & 15, quad = lane >> 4;
  const int wrow = ((w >> 1) << 6), wcol = ((w & 1) << 6);

  const f16* ap[4];
  const f16* bp[4];
#pragma unroll
  for (int mt = 0; mt < 4; mt++)
    ap[mt] = A + (size_t)(m0 + wrow + mt * 16 + l16) * K + quad * 8;
#pragma unroll
  for (int nt = 0; nt < 4; nt++)
    bp[nt] = Bt + (size_t)(n0 + wcol + nt * 16 + l16) * K + quad * 8;

  f32x4 acc[4][4] = {};
  f16x8 af[4], bf[4];
#pragma unroll
  for (int i = 0; i < 4; i++) {
    af[i] = *(const f16x8*)ap[i];
    bf[i] = *(const f16x8*)bp[i];
  }

#pragma unroll
  for (int k = 0; k < K / 32; k++) {
    f16x8 an[4], bn[4];
    if (k + 1 < K / 32) {
#pragma unroll
      for (int i = 0; i < 4; i++) {
        an[i] = *(const f16x8*)(ap[i] + (k + 1) * 32);
        bn[i] = *(const f16x8*)(bp[i] + (k + 1) * 32);
      }
    }
#pragma unroll
    for (int mt = 0; mt < 4; mt++)
#pragma unroll
      for (int nt = 0; nt < 4; nt++)
        acc[mt][nt] = __builtin_amdgcn_mfma_f32_16x16x32_f16(af[mt], bf[nt], acc[mt][nt], 0, 0, 0);
    if (k + 1 < K / 32) {
#pragma unroll
      for (int i = 0; i < 4; i++) { af[i] = an[i]; bf[i] = bn[i]; }
    }
  }

#pragma unroll
  for (int mt = 0; mt < 4; mt++)
#pragma unroll
    for (int nt = 0; nt < 4; nt++)
#pragma unroll
      for (int r = 0; r < 4; r++) {
        int row = m0 + wrow + mt * 16 + quad * 4 + r;
        int col = n0 + wcol + nt * 16 + l16;
        C[(size_t)row * N + col] = (CT)(acc[mt][nt][r] * scale);
      }
}

// Fused Q + KV projection GEMMs: blocks [0,256) -> Q (pre-scaled for
// log2-domain softmax), blocks [256,768) -> KV.
__global__ __launch_bounds__(256) void qkv_gemm(
    const f16* __restrict__ Xq, const f16* __restrict__ Wqt, f16* __restrict__ Qh,
    const f16* __restrict__ Xkv, const f16* __restrict__ Wkvt, f16* __restrict__ KVh,
    float sc_q) {
  if (blockIdx.x < 256)
    gemm_direct<1024, f16>(Xq, Wqt, Qh, blockIdx.x, 1024, sc_q);
  else
    gemm_direct<1024, f16>(Xkv, Wkvt, KVh, blockIdx.x - 256, 2048, 1.0f);
}

__global__ __launch_bounds__(256) void proj_gemm(
    const f16* __restrict__ A, const f16* __restrict__ Bt, float* __restrict__ C) {
  gemm_direct<1024, float>(A, Bt, C, blockIdx.x, 1024, 1.0f);
}

// ---------------------------------------------------------------------------
// Flash attention (unchanged from round 6/7 — control). 32x32x16 MFMA,
// transposed-S formulation; Qh pre-scaled by 8*log2(e); XCD-aware swizzle.
// ---------------------------------------------------------------------------
__global__ __launch_bounds__(256) void attn_kernel(
    const f16* __restrict__ Qh, const f16* __restrict__ KVh, f16* __restrict__ Yh) {
  __shared__ f16 smem[18432];
  f16* Ks = smem;                      // [64 kv][72]
  f16* Vt = smem + 64 * 72;            // [64 d][72] swizzled
  f16* Ps = smem + 2 * 64 * 72;        // 4 x [32 q][72]

  const int bid = blockIdx.x;
  const int hb = bid & 31;
  const int qt = bid >> 5;
  const int h = hb >> 1, b = hb & 1;
  const int tid = threadIdx.x;
  const int w = tid >> 6, lane = tid & 63;
  const int l31 = lane & 31, e = lane >> 5;

  const size_t qrow0 = (size_t)b * 2048 + (size_t)qt * 128;
  const size_t kvrow0 = (size_t)b * 2048;
  f16* Psw = Ps + w * 32 * 72;

  f16x8 qf[4];
#pragma unroll
  for (int ks = 0; ks < 4; ks++)
    qf[ks] = *(const f16x8*)&Qh[(qrow0 + w * 32 + l31) * 1024 + h * 64 + ks * 16 + e * 8];

  float m_run = -1e30f, l_run = 0.0f;
  f32x16 o_acc[2] = {};

  const int ksr = tid >> 2, ksc = (tid & 3) << 4;
  const int vkv0 = (tid >> 3) * 2;
  const int vd0 = (tid & 7) * 8;
  const int vcol = ((((vkv0 >> 3) ^ (tid & 7)) << 3) | (vkv0 & 7));

  f16x8 kr0, kr1, vr0, vr1;
  {
    const f16* kb = &KVh[(kvrow0 + ksr) * 2048 + h * 64 + ksc];
    kr0 = *(const f16x8*)kb;
    kr1 = *(const f16x8*)(kb + 8);
    const f16* vb = &KVh[(kvrow0 + vkv0) * 2048 + 1024 + h * 64 + vd0];
    vr0 = *(const f16x8*)vb;
    vr1 = *(const f16x8*)(vb + 2048);
  }

  for (int t = 0; t < 32; t++) {
    *(f16x8*)&Ks[ksr * 72 + ksc] = kr0;
    *(f16x8*)&Ks[ksr * 72 + ksc + 8] = kr1;
#pragma unroll
    for (int j = 0; j < 8; j++) {
      f16x2 p; p[0] = vr0[j]; p[1] = vr1[j];
      *(f16x2*)&Vt[(vd0 + j) * 72 + vcol] = p;
    }
    __syncthreads();

    if (t + 1 < 32) {
      const f16* kb = &KVh[(kvrow0 + (t + 1) * 64 + ksr) * 2048 + h * 64 + ksc];
      kr0 = *(const f16x8*)kb;
      kr1 = *(const f16x8*)(kb + 8);
      const f16* vb = &KVh[(kvrow0 + (t + 1) * 64 + vkv0) * 2048 + 1024 + h * 64 + vd0];
      vr0 = *(const f16x8*)vb;
      vr1 = *(const f16x8*)(vb + 2048);
    }

    f32x16 sacc[2] = {};
#pragma unroll
    for (int kvt = 0; kvt < 2; kvt++)
#pragma unroll
      for (int ks = 0; ks < 4; ks++) {
        f16x8 a = *(const f16x8*)&Ks[(kvt * 32 + l31) * 72 + ks * 16 + e * 8];
        sacc[kvt] = __builtin_amdgcn_mfma_f32_32x32x16_f16(a, qf[ks], sacc[kvt], 0, 0, 0);
      }

    float mx = sacc[0][0];
#pragma unroll
    for (int r = 1; r < 16; r++) mx = fmaxf(mx, sacc[0][r]);
#pragma unroll
    for (int r = 0; r < 16; r++) mx = fmaxf(mx, sacc[1][r]);
    mx = fmaxf(mx, __shfl_xor(mx, 32, 64));
    float mnew = fmaxf(m_run, mx);
    float alpha = exp2_fast(m_run - mnew);
    m_run = mnew;

    float ssum = 0.0f;
#pragma unroll
    for (int kvt = 0; kvt < 2; kvt++)
#pragma unroll
      for (int r = 0; r < 16; r++) {
        float p = exp2_fast(sacc[kvt][r] - mnew);
        sacc[kvt][r] = p;
        ssum += p;
      }
    ssum += __shfl_xor(ssum, 32, 64);
    l_run = l_run * alpha + ssum;
#pragma unroll
    for (int r = 0; r < 16; r++) { o_acc[0][r] *= alpha; o_acc[1][r] *= alpha; }

#pragma unroll
    for (int kvt = 0; kvt < 2; kvt++)
#pragma unroll
      for (int r2 = 0; r2 < 4; r2++) {
        f16x4 hh;
        hh[0] = (f16)sacc[kvt][r2 * 4 + 0];
        hh[1] = (f16)sacc[kvt][r2 * 4 + 1];
        hh[2] = (f16)sacc[kvt][r2 * 4 + 2];
        hh[3] = (f16)sacc[kvt][r2 * 4 + 3];
        *(f16x4*)&Psw[l31 * 72 + kvt * 32 + r2 * 8 + e * 4] = hh;
      }

    f16x8 pf[4];
#pragma unroll
    for (int ks = 0; ks < 4; ks++)
      pf[ks] = *(const f16x8*)&Psw[l31 * 72 + ks * 16 + e * 8];
#pragma unroll
    for (int dt = 0; dt < 2; dt++) {
      const int d = dt * 32 + l31;
      const int dx = d >> 3;
#pragma unroll
      for (int ks = 0; ks < 4; ks++) {
        f16x8 va = *(const f16x8*)&Vt[d * 72 + (((ks * 2 + e) ^ dx) << 3)];
        o_acc[dt] = __builtin_amdgcn_mfma_f32_32x32x16_f16(va, pf[ks], o_acc[dt], 0, 0, 0);
      }
    }
    __syncthreads();
  }

  float linv = 1.0f / l_run;
  float* Of = (float*)smem + w * 2176;  // [32 q][68]
#pragma unroll
  for (int dt = 0; dt < 2; dt++)
#pragma unroll
    for (int r2 = 0; r2 < 4; r2++) {
      f32x4 vv;
      vv[0] = o_acc[dt][r2 * 4 + 0] * linv;
      vv[1] = o_acc[dt][r2 * 4 + 1] * linv;
      vv[2] = o_acc[dt][r2 * 4 + 2] * linv;
      vv[3] = o_acc[dt][r2 * 4 + 3] * linv;
      *(f32x4*)&Of[l31 * 68 + dt * 32 + r2 * 8 + e * 4] = vv;
    }
  const int qq = lane >> 1, dh = (lane & 1) * 32;
#pragma unroll
  for (int j = 0; j < 8; j++) {
    f32x4 v = *(const f32x4*)&Of[qq * 68 + dh + j * 4];
    f16x4 hh;
    hh[0] = (f16)v[0]; hh[1] = (f16)v[1]; hh[2] = (f16)v[2]; hh[3] = (f16)v[3];
    *(f16x4*)&Yh[(qrow0 + w * 32 + qq) * 1024 + h * 64 + dh + j * 4] = hh;
  }
}

// ---------------------------------------------------------------------------
extern "C" void kernel_launch(void* const* d_in, const int* in_sizes, int n_in,
                              void* d_out, int out_size, void* d_ws, size_t ws_size,
                              hipStream_t stream) {
  const float* x_q  = (const float*)d_in[0];
  const float* x_kv = (const float*)d_in[1];
  const float* W_q  = (const float*)d_in[2];
  const float* W_kv = (const float*)d_in[3];
  const float* W_p  = (const float*)d_in[4];
  float* out = (float*)d_out;

  f16* Wq_t  = (f16*)d_ws;                       // [1024][1024]
  f16* Wkv_t = Wq_t  + (size_t)1024 * 1024;      // [2048][1024]
  f16* Wp_t  = Wkv_t + (size_t)2048 * 1024;      // [1024][1024]
  f16* Qh    = Wp_t  + (size_t)1024 * 1024;      // [4096][1024]
  f16* KVh   = Qh    + (size_t)4096 * 1024;      // [4096][2048]
  f16* Yh    = KVh   + (size_t)4096 * 2048;      // [4096][1024]
  f16* Xq_h  = Yh;                               // alias (dead after qkv_gemm)
  f16* Xkv_h = Yh    + (size_t)4096 * 1024;      // [4096][1024]

  prep<<<12288, 256, 0, stream>>>(x_q, x_kv, Xq_h, Xkv_h,
                                  W_q, W_kv, W_p, Wq_t, Wkv_t, Wp_t);

  const float SC = 11.5415603f;  // 8 * log2(e)
  qkv_gemm<<<768, 256, 0, stream>>>(Xq_h, Wq_t, Qh, Xkv_h, Wkv_t, KVh, SC);

  attn_kernel<<<512, 256, 0, stream>>>(Qh, KVh, Yh);

  proj_gemm<<<256, 256, 0, stream>>>(Yh, Wp_t, out);
}